// Round 1
// baseline (22823.027 us; speedup 1.0000x reference)
//
#include <hip/hip_runtime.h>
#include <cstddef>
#include <cstdint>

// Problem constants (match reference)
#define B_     2
#define S_     2048
#define HID_   2048
#define NH_    16
#define HD_    128
#define NE_    8
#define INTER_ 4096
#define T_     (B_ * S_)   // 4096 tokens

__device__ __forceinline__ float4 ld4(const float* p) {
    return *reinterpret_cast<const float4*>(p);
}
__device__ __forceinline__ void st4(float* p, float4 v) {
    *reinterpret_cast<float4*>(p) = v;
}

// ---------------------------------------------------------------- zero counts
__global__ void zero_counts_k(int* cnt) {
    if (threadIdx.x < NE_) cnt[threadIdx.x] = 0;
}

// ---------------------------------------------------------------- rmsnorm
// one block per row of [T_, HID_]; 256 threads * 8 floats
__global__ __launch_bounds__(256)
void rmsnorm_k(const float* __restrict__ x, const float* __restrict__ w,
               float* __restrict__ o) {
    const int row = blockIdx.x;
    const int t = threadIdx.x;
    const float* xr = x + (size_t)row * HID_;
    float4 v0 = ld4(xr + t * 8);
    float4 v1 = ld4(xr + t * 8 + 4);
    float ss = v0.x*v0.x + v0.y*v0.y + v0.z*v0.z + v0.w*v0.w
             + v1.x*v1.x + v1.y*v1.y + v1.z*v1.z + v1.w*v1.w;
    #pragma unroll
    for (int off = 32; off >= 1; off >>= 1) ss += __shfl_xor(ss, off);
    __shared__ float red[4];
    if ((t & 63) == 0) red[t >> 6] = ss;
    __syncthreads();
    float tot = red[0] + red[1] + red[2] + red[3];
    float r = rsqrtf(tot * (1.0f / (float)HID_) + 1e-5f);
    float4 w0 = ld4(w + t * 8);
    float4 w1 = ld4(w + t * 8 + 4);
    float4 o0 = make_float4(v0.x*r*w0.x, v0.y*r*w0.y, v0.z*r*w0.z, v0.w*r*w0.w);
    float4 o1 = make_float4(v1.x*r*w1.x, v1.y*r*w1.y, v1.z*r*w1.z, v1.w*r*w1.w);
    float* orow = o + (size_t)row * HID_;
    st4(orow + t * 8, o0);
    st4(orow + t * 8 + 4, o1);
}

// ---------------------------------------------------------------- generic NT GEMM
// C[M,N] = A[M,K] * B0[N,K]^T  (both row-major, reduction along fast axis)
// BM=128, BN=64, BK=32, 256 threads, 8x4 micro-tile.
// STORE modes:
//   ST_PLAIN   : C = acc
//   ST_RESID   : C = D + acc
//   ST_SCATTER : Out[rmap[m]] += rw[m] * acc   (m < *cntp only; atomicAdd)
//   ST_GU      : dual-B (B0=Wg, B1=Wu); C = silu(acc0) * acc1
// AMAP: A rows are gathered through rmap (expert token list); rows >= *cntp load 0.
#define BM 128
#define BN 64
#define BKT 32

enum { ST_PLAIN = 0, ST_RESID = 1, ST_SCATTER = 2, ST_GU = 3 };

template<int STORE, bool AMAP>
__global__ __launch_bounds__(256)
void gemm_nt_k(const float* __restrict__ A, const float* __restrict__ B0,
               const float* __restrict__ B1, float* __restrict__ C,
               const float* __restrict__ D, int M, int N, int K,
               const int* __restrict__ rmap, const float* __restrict__ rw,
               const int* __restrict__ cntp, float* __restrict__ Out) {
    constexpr bool DUAL = (STORE == ST_GU);
    const int tile_m = blockIdx.x;
    const int tile_n = blockIdx.y;
    int cnt = M;
    if (cntp) {
        cnt = *cntp;                       // device-side count (graph-safe)
        if (tile_m * BM >= cnt) return;    // dead tile
    }
    // K-major LDS tiles (transposed on store) -> float4 reads in inner loop.
    __shared__ float As[BKT][BM + 4];
    __shared__ float Bs0[BKT][BN + 4];
    __shared__ float Bs1[DUAL ? BKT : 1][BN + 4];

    const int tid = threadIdx.x;
    const int tc = tid & 15;   // col group (*4 cols)
    const int tr = tid >> 4;   // row group (*8 rows)

    float acc0[8][4] = {};
    float acc1[DUAL ? 8 : 1][4] = {};

    const int nkt = K / BKT;
    for (int kt = 0; kt < nkt; ++kt) {
        const int k0 = kt * BKT;
        float4 aReg[4], bReg0[2], bReg1[2];
        #pragma unroll
        for (int i = 0; i < 4; ++i) {      // A tile: 128x32 = 1024 float4
            int idx = tid + i * 256;
            int ar = idx >> 3, ak4 = idx & 7;
            int grow = tile_m * BM + ar;
            if (AMAP) {
                if (grow < cnt) {
                    int srow = rmap[grow];
                    aReg[i] = ld4(A + (size_t)srow * K + k0 + ak4 * 4);
                } else {
                    aReg[i] = make_float4(0.f, 0.f, 0.f, 0.f);
                }
            } else {
                aReg[i] = ld4(A + (size_t)grow * K + k0 + ak4 * 4);
            }
        }
        #pragma unroll
        for (int i = 0; i < 2; ++i) {      // B tile: 64x32 = 512 float4
            int idx = tid + i * 256;
            int br = idx >> 3, bk4 = idx & 7;
            size_t boff = (size_t)(tile_n * BN + br) * K + k0 + bk4 * 4;
            bReg0[i] = ld4(B0 + boff);
            if constexpr (DUAL) bReg1[i] = ld4(B1 + boff);
        }
        __syncthreads();
        #pragma unroll
        for (int i = 0; i < 4; ++i) {
            int idx = tid + i * 256;
            int ar = idx >> 3, ak4 = idx & 7;
            As[ak4 * 4 + 0][ar] = aReg[i].x;
            As[ak4 * 4 + 1][ar] = aReg[i].y;
            As[ak4 * 4 + 2][ar] = aReg[i].z;
            As[ak4 * 4 + 3][ar] = aReg[i].w;
        }
        #pragma unroll
        for (int i = 0; i < 2; ++i) {
            int idx = tid + i * 256;
            int br = idx >> 3, bk4 = idx & 7;
            Bs0[bk4 * 4 + 0][br] = bReg0[i].x;
            Bs0[bk4 * 4 + 1][br] = bReg0[i].y;
            Bs0[bk4 * 4 + 2][br] = bReg0[i].z;
            Bs0[bk4 * 4 + 3][br] = bReg0[i].w;
            if constexpr (DUAL) {
                Bs1[bk4 * 4 + 0][br] = bReg1[i].x;
                Bs1[bk4 * 4 + 1][br] = bReg1[i].y;
                Bs1[bk4 * 4 + 2][br] = bReg1[i].z;
                Bs1[bk4 * 4 + 3][br] = bReg1[i].w;
            }
        }
        __syncthreads();
        #pragma unroll
        for (int k = 0; k < BKT; ++k) {
            float4 a0 = *(const float4*)&As[k][tr * 8];
            float4 a1 = *(const float4*)&As[k][tr * 8 + 4];
            float4 b0 = *(const float4*)&Bs0[k][tc * 4];
            float av[8] = {a0.x, a0.y, a0.z, a0.w, a1.x, a1.y, a1.z, a1.w};
            float bv[4] = {b0.x, b0.y, b0.z, b0.w};
            #pragma unroll
            for (int i = 0; i < 8; ++i)
                #pragma unroll
                for (int j = 0; j < 4; ++j)
                    acc0[i][j] = fmaf(av[i], bv[j], acc0[i][j]);
            if constexpr (DUAL) {
                float4 b1 = *(const float4*)&Bs1[k][tc * 4];
                float bv1[4] = {b1.x, b1.y, b1.z, b1.w};
                #pragma unroll
                for (int i = 0; i < 8; ++i)
                    #pragma unroll
                    for (int j = 0; j < 4; ++j)
                        acc1[i][j] = fmaf(av[i], bv1[j], acc1[i][j]);
            }
        }
    }

    const int ccol = tile_n * BN + tc * 4;
    #pragma unroll
    for (int i = 0; i < 8; ++i) {
        const int row = tile_m * BM + tr * 8 + i;
        if constexpr (STORE == ST_SCATTER) {
            if (row < cnt) {
                int orow = rmap[row];
                float wgt = rw[row];
                float* dst = Out + (size_t)orow * N + ccol;
                atomicAdd(dst + 0, wgt * acc0[i][0]);
                atomicAdd(dst + 1, wgt * acc0[i][1]);
                atomicAdd(dst + 2, wgt * acc0[i][2]);
                atomicAdd(dst + 3, wgt * acc0[i][3]);
            }
        } else {
            float4 r;
            if constexpr (STORE == ST_GU) {
                float g0 = acc0[i][0], g1 = acc0[i][1], g2 = acc0[i][2], g3 = acc0[i][3];
                r.x = (g0 / (1.f + __expf(-g0))) * acc1[i][0];
                r.y = (g1 / (1.f + __expf(-g1))) * acc1[i][1];
                r.z = (g2 / (1.f + __expf(-g2))) * acc1[i][2];
                r.w = (g3 / (1.f + __expf(-g3))) * acc1[i][3];
            } else {
                r = make_float4(acc0[i][0], acc0[i][1], acc0[i][2], acc0[i][3]);
                if constexpr (STORE == ST_RESID) {
                    float4 d = ld4(D + (size_t)row * N + ccol);
                    r.x += d.x; r.y += d.y; r.z += d.z; r.w += d.w;
                }
            }
            st4(C + (size_t)row * N + ccol, r);
        }
    }
}

// ---------------------------------------------------------------- flash attention (fp32, causal)
// grid: (S/32, B*NH). One block = one (b, h, 32-row Q tile). 256 threads.
// Q/K/V layout: [T, HID] with col = h*128 + d.
__global__ __launch_bounds__(256)
void attn_k(const float* __restrict__ Q, const float* __restrict__ K,
            const float* __restrict__ V, float* __restrict__ O) {
    const int qt = blockIdx.x;
    const int bh = blockIdx.y;
    const int b = bh >> 4, h = bh & 15;
    const int t0 = b * S_;
    const int q0 = qt * 32;

    __shared__ float Qs[32][132];
    __shared__ float Ks[32][132];
    __shared__ float Vs[32][132];
    __shared__ float Ss[32][33];

    const int tid = threadIdx.x;
    // load Q tile (32 x 128)
    #pragma unroll
    for (int i = 0; i < 4; ++i) {
        int idx = tid + i * 256;
        int r = idx >> 5, c4 = idx & 31;
        float4 qv = ld4(Q + (size_t)(t0 + q0 + r) * HID_ + h * HD_ + c4 * 4);
        *(float4*)&Qs[r][c4 * 4] = qv;
    }

    const int sq  = tid >> 3;       // score/O row (0..31)
    const int kg  = tid & 7;        // score col group: ki = kg + 8j
    const int od0 = (tid & 7) * 16; // O col slice

    float m = -1e30f, l = 0.f;
    float o[16];
    #pragma unroll
    for (int j = 0; j < 16; ++j) o[j] = 0.f;
    const float scale = 0.08838834764831845f;

    const int nkt = qt + 1;
    for (int kt = 0; kt < nkt; ++kt) {
        const int k0 = kt * 32;
        __syncthreads();   // prev-iter Ks/Vs reads complete
        #pragma unroll
        for (int i = 0; i < 4; ++i) {
            int idx = tid + i * 256;
            int r = idx >> 5, c4 = idx & 31;
            *(float4*)&Ks[r][c4 * 4] = ld4(K + (size_t)(t0 + k0 + r) * HID_ + h * HD_ + c4 * 4);
            *(float4*)&Vs[r][c4 * 4] = ld4(V + (size_t)(t0 + k0 + r) * HID_ + h * HD_ + c4 * 4);
        }
        __syncthreads();
        // scores: 4 per thread (ki = kg + 8j)
        float s[4] = {0.f, 0.f, 0.f, 0.f};
        #pragma unroll 8
        for (int d4 = 0; d4 < 32; ++d4) {
            float4 qv = *(const float4*)&Qs[sq][d4 * 4];
            #pragma unroll
            for (int j = 0; j < 4; ++j) {
                float4 kv = *(const float4*)&Ks[kg + 8 * j][d4 * 4];
                s[j] += qv.x*kv.x + qv.y*kv.y + qv.z*kv.z + qv.w*kv.w;
            }
        }
        float mx = -1e30f;
        #pragma unroll
        for (int j = 0; j < 4; ++j) {
            s[j] *= scale;
            if (k0 + kg + 8 * j > q0 + sq) s[j] = -1e30f;  // causal mask
            mx = fmaxf(mx, s[j]);
        }
        #pragma unroll
        for (int off = 1; off < 8; off <<= 1) mx = fmaxf(mx, __shfl_xor(mx, off));
        float mnew = fmaxf(m, mx);
        float alpha = __expf(m - mnew);
        float ps = 0.f;
        #pragma unroll
        for (int j = 0; j < 4; ++j) {
            float p = __expf(s[j] - mnew);
            ps += p;
            Ss[sq][kg + 8 * j] = p;   // same-wave producer/consumer, no barrier needed
        }
        #pragma unroll
        for (int off = 1; off < 8; off <<= 1) ps += __shfl_xor(ps, off);
        l = l * alpha + ps;
        m = mnew;
        // PV
        #pragma unroll
        for (int j = 0; j < 16; ++j) o[j] *= alpha;
        #pragma unroll 8
        for (int ki = 0; ki < 32; ++ki) {
            float p = Ss[sq][ki];
            float4 v0 = *(const float4*)&Vs[ki][od0 + 0];
            float4 v1 = *(const float4*)&Vs[ki][od0 + 4];
            float4 v2 = *(const float4*)&Vs[ki][od0 + 8];
            float4 v3 = *(const float4*)&Vs[ki][od0 + 12];
            o[0]  = fmaf(p, v0.x, o[0]);  o[1]  = fmaf(p, v0.y, o[1]);
            o[2]  = fmaf(p, v0.z, o[2]);  o[3]  = fmaf(p, v0.w, o[3]);
            o[4]  = fmaf(p, v1.x, o[4]);  o[5]  = fmaf(p, v1.y, o[5]);
            o[6]  = fmaf(p, v1.z, o[6]);  o[7]  = fmaf(p, v1.w, o[7]);
            o[8]  = fmaf(p, v2.x, o[8]);  o[9]  = fmaf(p, v2.y, o[9]);
            o[10] = fmaf(p, v2.z, o[10]); o[11] = fmaf(p, v2.w, o[11]);
            o[12] = fmaf(p, v3.x, o[12]); o[13] = fmaf(p, v3.y, o[13]);
            o[14] = fmaf(p, v3.z, o[14]); o[15] = fmaf(p, v3.w, o[15]);
        }
    }
    const float inv = 1.f / l;
    float* dst = O + (size_t)(t0 + q0 + sq) * HID_ + h * HD_ + od0;
    st4(dst + 0,  make_float4(o[0]*inv,  o[1]*inv,  o[2]*inv,  o[3]*inv));
    st4(dst + 4,  make_float4(o[4]*inv,  o[5]*inv,  o[6]*inv,  o[7]*inv));
    st4(dst + 8,  make_float4(o[8]*inv,  o[9]*inv,  o[10]*inv, o[11]*inv));
    st4(dst + 12, make_float4(o[12]*inv, o[13]*inv, o[14]*inv, o[15]*inv));
}

// ---------------------------------------------------------------- router: logits, top-2, softmax, list append
// one wave per token; 4 tokens per 256-thread block
__global__ __launch_bounds__(256)
void router_k(const float* __restrict__ xn2, const float* __restrict__ Wr,
              int* __restrict__ cnt, int* __restrict__ list,
              float* __restrict__ wl) {
    const int token = blockIdx.x * 4 + (threadIdx.x >> 6);
    const int lane = threadIdx.x & 63;
    const float* xr = xn2 + (size_t)token * HID_;
    float acc[NE_] = {};
    for (int i = lane; i < HID_; i += 64) {
        float xv = xr[i];
        #pragma unroll
        for (int e = 0; e < NE_; ++e) acc[e] = fmaf(xv, Wr[e * HID_ + i], acc[e]);
    }
    #pragma unroll
    for (int e = 0; e < NE_; ++e)
        #pragma unroll
        for (int off = 1; off < 64; off <<= 1) acc[e] += __shfl_xor(acc[e], off);
    if (lane == 0) {
        int e0 = 0; float v0 = acc[0];
        #pragma unroll
        for (int e = 1; e < NE_; ++e) if (acc[e] > v0) { v0 = acc[e]; e0 = e; }
        int e1 = -1; float v1 = -1e30f;
        #pragma unroll
        for (int e = 0; e < NE_; ++e) if (e != e0 && acc[e] > v1) { v1 = acc[e]; e1 = e; }
        float p0 = 1.f / (1.f + __expf(v1 - v0));   // softmax over the two top logits
        float p1 = 1.f - p0;
        int pos0 = atomicAdd(&cnt[e0], 1);
        list[e0 * T_ + pos0] = token; wl[e0 * T_ + pos0] = p0;
        int pos1 = atomicAdd(&cnt[e1], 1);
        list[e1 * T_ + pos1] = token; wl[e1 * T_ + pos1] = p1;
    }
}

// ---------------------------------------------------------------- launch
extern "C" void kernel_launch(void* const* d_in, const int* in_sizes, int n_in,
                              void* d_out, int out_size, void* d_ws, size_t ws_size,
                              hipStream_t stream) {
    (void)in_sizes; (void)n_in; (void)out_size; (void)ws_size;
    const float* x    = (const float*)d_in[0];
    const float* Wq   = (const float*)d_in[1];
    const float* Wk   = (const float*)d_in[2];
    const float* Wv   = (const float*)d_in[3];
    const float* Wo   = (const float*)d_in[4];
    const float* wln1 = (const float*)d_in[5];
    const float* wln2 = (const float*)d_in[6];
    const float* Wr   = (const float*)d_in[7];
    const float* Wg   = (const float*)d_in[8];
    const float* Wu   = (const float*)d_in[9];
    const float* Wd   = (const float*)d_in[10];
    float* out = (float*)d_out;

    // workspace layout (floats): [xn | q | k | v | small]
    // xn (8M) also reused as attention output h; q (8M) reused as xn2;
    // act (16M) aliases [k, v] (dead after attention). Total ~128.3 MB.
    float* ws = (float*)d_ws;
    const size_t MB8 = (size_t)T_ * HID_;   // 8M floats
    float* xn  = ws;
    float* q   = ws + MB8;
    float* kk  = ws + 2 * MB8;
    float* vv  = ws + 3 * MB8;
    float* act = kk;
    char* sm = (char*)(ws + 4 * MB8);
    int*   cnt  = (int*)sm;
    int*   list = (int*)(sm + 256);
    float* wl   = (float*)(sm + 256 + sizeof(int) * (size_t)NE_ * T_);

    zero_counts_k<<<1, 64, 0, stream>>>(cnt);
    rmsnorm_k<<<T_, 256, 0, stream>>>(x, wln1, xn);

    dim3 gQKV(T_ / BM, HID_ / BN);   // (32, 32)
    gemm_nt_k<ST_PLAIN, false><<<gQKV, 256, 0, stream>>>(
        xn, Wq, nullptr, q, nullptr, T_, HID_, HID_, nullptr, nullptr, nullptr, nullptr);
    gemm_nt_k<ST_PLAIN, false><<<gQKV, 256, 0, stream>>>(
        xn, Wk, nullptr, kk, nullptr, T_, HID_, HID_, nullptr, nullptr, nullptr, nullptr);
    gemm_nt_k<ST_PLAIN, false><<<gQKV, 256, 0, stream>>>(
        xn, Wv, nullptr, vv, nullptr, T_, HID_, HID_, nullptr, nullptr, nullptr, nullptr);

    attn_k<<<dim3(S_ / 32, B_ * NH_), 256, 0, stream>>>(q, kk, vv, xn);  // h -> xn

    gemm_nt_k<ST_RESID, false><<<gQKV, 256, 0, stream>>>(
        xn, Wo, nullptr, out, x, T_, HID_, HID_, nullptr, nullptr, nullptr, nullptr);

    rmsnorm_k<<<T_, 256, 0, stream>>>(out, wln2, q);  // xn2 -> q
    router_k<<<T_ / 4, 256, 0, stream>>>(q, Wr, cnt, list, wl);

    for (int e = 0; e < NE_; ++e) {
        gemm_nt_k<ST_GU, true><<<dim3(T_ / BM, INTER_ / BN), 256, 0, stream>>>(
            q, Wg + (size_t)e * INTER_ * HID_, Wu + (size_t)e * INTER_ * HID_,
            act, nullptr, T_, INTER_, HID_,
            list + e * T_, nullptr, cnt + e, nullptr);
        gemm_nt_k<ST_SCATTER, false><<<dim3(T_ / BM, HID_ / BN), 256, 0, stream>>>(
            act, Wd + (size_t)e * HID_ * INTER_, nullptr, nullptr, nullptr,
            T_, HID_, INTER_,
            list + e * T_, wl + e * T_, cnt + e, out);
    }
}